// Round 3
// baseline (738.341 us; speedup 1.0000x reference)
//
#include <hip/hip_runtime.h>

typedef unsigned short u16;
typedef __attribute__((ext_vector_type(4))) unsigned short u16x4;
typedef __attribute__((ext_vector_type(8))) unsigned short u16x8;
typedef __attribute__((ext_vector_type(4))) float f32x4;
typedef __attribute__((ext_vector_type(8))) __bf16 bf16x8;

__device__ __forceinline__ u16 f2bf(float f) {
  union { float f; unsigned int u; } v; v.f = f;
  unsigned int u = v.u;
  unsigned int r = (u + 0x7fffu + ((u >> 16) & 1u)) >> 16;
  return (u16)r;
}
__device__ __forceinline__ float bf2f(u16 h) {
  union { unsigned int u; float f; } v; v.u = ((unsigned int)h) << 16;
  return v.f;
}
__device__ __forceinline__ f32x4 mfma16(u16x8 a, u16x8 b, f32x4 c) {
  return __builtin_amdgcn_mfma_f32_16x16x32_bf16(
      __builtin_bit_cast(bf16x8, a), __builtin_bit_cast(bf16x8, b), c, 0, 0, 0);
}
// async global->LDS, 16B per lane; LDS dest = wave-uniform base + lane*16
__device__ __forceinline__ void glds16(const void* g, void* l) {
  __builtin_amdgcn_global_load_lds((const __attribute__((address_space(1))) void*)g,
                                   (__attribute__((address_space(3))) void*)l, 16, 0, 0);
}

// ---------------- fp32 -> bf16 conversion ----------------
__global__ __launch_bounds__(256) void cvt_bf16(const float* __restrict__ x,
                                                u16* __restrict__ y, int n4) {
  int i = blockIdx.x * 256 + threadIdx.x;
  if (i >= n4) return;
  float4 v = ((const float4*)x)[i];
  u16x4 o;
  o.x = f2bf(v.x); o.y = f2bf(v.y); o.z = f2bf(v.z); o.w = f2bf(v.w);
  ((u16x4*)y)[i] = o;
}
// 4 weight matrices in one launch (blockIdx.y selects)
__global__ __launch_bounds__(256) void cvt_w4(const float* __restrict__ a, const float* __restrict__ b,
                                              const float* __restrict__ c, const float* __restrict__ d,
                                              u16* __restrict__ oa, u16* __restrict__ ob,
                                              u16* __restrict__ oc, u16* __restrict__ od) {
  int w = blockIdx.y;
  const float* s = w == 0 ? a : w == 1 ? b : w == 2 ? c : d;
  u16* o = w == 0 ? oa : w == 1 ? ob : w == 2 ? oc : od;
  int i = blockIdx.x * 256 + threadIdx.x;
  float4 v = ((const float4*)s)[i];
  u16x4 r;
  r.x = f2bf(v.x); r.y = f2bf(v.y); r.z = f2bf(v.z); r.w = f2bf(v.w);
  ((u16x4*)o)[i] = r;
}

// ---------------- GEMM: C[M,1536] = A[M,1536] @ W[1536,1536]^T + bias ----------------
// BK=64, global_load_lds staging, XOR chunk swizzle.
// OUT: 0 = bf16 row-major, 1 = f32 row-major, 2 = bf16 transposed (C^T[N][ldt])
template <int OUT>
__global__ __launch_bounds__(256, 3) void gemm_v2(
    const u16* __restrict__ A, const u16* __restrict__ W,
    const float* __restrict__ bias, void* __restrict__ Cp, int M, int ldt) {
  const int K = 1536, N = 1536;
  __shared__ __align__(16) u16 gsm[17408];  // As[128][64] | Bs[128][64]; epi reuses as Ct[128][136]
  u16* As = gsm;
  u16* Bs = gsm + 8192;
  const int tid = threadIdx.x;
  const int lane = tid & 63, wid = tid >> 6;
  const int quad = lane >> 4, l15 = lane & 15;
  const int m0 = blockIdx.y * 128, n0 = blockIdx.x * 128;
  const int wm = (wid >> 1) * 64, wn = (wid & 1) * 64;
  f32x4 acc[4][4];
#pragma unroll
  for (int i = 0; i < 4; ++i)
#pragma unroll
    for (int j = 0; j < 4; ++j)
#pragma unroll
      for (int r = 0; r < 4; ++r) acc[i][j][r] = 0.f;

  const int r8 = lane >> 3, c8 = lane & 7;
  const int gch = c8 ^ r8;  // swizzled global 16B-chunk for this lane

  for (int k0 = 0; k0 < K; k0 += 64) {
#pragma unroll
    for (int inst = 0; inst < 4; ++inst) {
      int row = wid * 32 + inst * 8 + r8;
      glds16(A + ((size_t)(m0 + row) * K + k0 + gch * 8), As + (wid * 32 + inst * 8) * 64);
      glds16(W + ((size_t)(n0 + row) * K + k0 + gch * 8), Bs + (wid * 32 + inst * 8) * 64);
    }
    asm volatile("s_waitcnt vmcnt(0)" ::: "memory");
    __syncthreads();
#pragma unroll
    for (int ks = 0; ks < 2; ++ks) {
      u16x8 af[4], bfr[4];
#pragma unroll
      for (int i = 0; i < 4; ++i) {
        int row = wm + i * 16 + l15;
        af[i] = *(const u16x8*)&As[row * 64 + (((ks * 4 + quad) ^ (l15 & 7)) * 8)];
      }
#pragma unroll
      for (int j = 0; j < 4; ++j) {
        int row = wn + j * 16 + l15;
        bfr[j] = *(const u16x8*)&Bs[row * 64 + (((ks * 4 + quad) ^ (l15 & 7)) * 8)];
      }
#pragma unroll
      for (int i = 0; i < 4; ++i)
#pragma unroll
        for (int j = 0; j < 4; ++j) acc[i][j] = mfma16(af[i], bfr[j], acc[i][j]);
    }
    __syncthreads();
  }

  if (OUT != 2) {
#pragma unroll
    for (int i = 0; i < 4; ++i) {
      int row = m0 + wm + i * 16 + quad * 4;
#pragma unroll
      for (int j = 0; j < 4; ++j) {
        int col = n0 + wn + j * 16 + l15;
        float bc = bias[col];
#pragma unroll
        for (int r = 0; r < 4; ++r) {
          if (row + r < M) {
            float v = acc[i][j][r] + bc;
            if (OUT == 1)
              ((float*)Cp)[(size_t)(row + r) * N + col] = v;
            else
              ((u16*)Cp)[(size_t)(row + r) * N + col] = f2bf(v);
          }
        }
      }
    }
  } else {
    // transposed epilogue: stage C^T tile via LDS, write coalesced along m
    u16* Ct = gsm;  // [128 n][136]
#pragma unroll
    for (int i = 0; i < 4; ++i)
#pragma unroll
      for (int j = 0; j < 4; ++j) {
        int nloc = wn + j * 16 + l15;
        float bc = bias[n0 + nloc];
#pragma unroll
        for (int r = 0; r < 4; ++r) {
          int mloc = wm + i * 16 + quad * 4 + r;
          Ct[nloc * 136 + mloc] = f2bf(acc[i][j][r] + bc);
        }
      }
    __syncthreads();
    int n = tid >> 1, half = tid & 1;
#pragma unroll
    for (int e = 0; e < 8; ++e) {
      int mloc = half * 64 + e * 8;
      if (m0 + mloc < M) {
        u16x8 v = *(const u16x8*)&Ct[n * 136 + mloc];
        *(u16x8*)((u16*)Cp + (size_t)(n0 + n) * ldt + m0 + mloc) = v;
      }
    }
  }
}

// ---------------- fused RMSNorm + interleaved RoPE, in-place bf16 ----------------
__global__ __launch_bounds__(192) void norm_rope2(u16* __restrict__ X,
                                                  const float* __restrict__ g,
                                                  const float* __restrict__ fc,
                                                  const float* __restrict__ fs,
                                                  float oscale) {
  const int DIMc = 1536;
  int row = blockIdx.x;
  int tid = threadIdx.x;
  u16* xr = X + (size_t)row * DIMc + tid * 8;
  u16x8 v = *(const u16x8*)xr;
  float x[8];
  float ss = 0.f;
#pragma unroll
  for (int e = 0; e < 8; ++e) { x[e] = bf2f(v[e]); ss += x[e] * x[e]; }
#pragma unroll
  for (int m = 1; m < 64; m <<= 1) ss += __shfl_xor(ss, m);
  __shared__ float w3[3];
  if ((tid & 63) == 0) w3[tid >> 6] = ss;
  __syncthreads();
  float rs = rsqrtf((w3[0] + w3[1] + w3[2]) * (1.f / 1536.f) + 1e-5f);
  int dhb = (tid * 8) & 127;
  const float* fcr = fc + (size_t)row * 128 + dhb;
  const float* fsr = fs + (size_t)row * 128 + dhb;
  float4 c0 = *(const float4*)fcr, c1 = *(const float4*)(fcr + 4);
  float4 s0 = *(const float4*)fsr, s1 = *(const float4*)(fsr + 4);
  const float* gp = g + tid * 8;
  float4 g0 = *(const float4*)gp, g1 = *(const float4*)(gp + 4);
  float cosv[4] = {c0.x, c0.z, c1.x, c1.z};
  float sinv[4] = {s0.y, s0.w, s1.y, s1.w};
  float gv[8] = {g0.x, g0.y, g0.z, g0.w, g1.x, g1.y, g1.z, g1.w};
  u16x8 o;
#pragma unroll
  for (int p = 0; p < 4; ++p) {
    float a = x[2 * p] * rs * gv[2 * p];
    float b = x[2 * p + 1] * rs * gv[2 * p + 1];
    o[2 * p] = f2bf((a * cosv[p] - b * sinv[p]) * oscale);
    o[2 * p + 1] = f2bf((a * sinv[p] + b * cosv[p]) * oscale);
  }
  *(u16x8*)xr = o;
}

// ---------------- block-sparse attention v3 ----------------
// 1-D grid 600, XCD-swizzled so all 25 q-tiles of one (h,t) share an XCD.
// Double-buffered K/V staging; raw barriers so prefetch stays in flight.
__global__ __launch_bounds__(256, 2) void attn3(
    const u16* __restrict__ Q, const u16* __restrict__ Kb,
    const u16* __restrict__ VT, const int* __restrict__ sel,
    u16* __restrict__ O) {
  const int HWc = 1560, DIMc = 1536, KTt = 12480;
  // Ks0 | Ks1 | Vt0 | Vt1 | Ps : 16KB x4 + 8.5KB
  __shared__ __align__(16) u16 smem[4 * 8192 + 4352];
  __shared__ float Ls[4][64];
  u16* Ps = smem + 32768;
  const int tid = threadIdx.x;
  const int lane = tid & 63, wid = tid >> 6;
  const int quad = lane >> 4, l15 = lane & 15;

  // XCD swizzle: xcd = bid&7 hosts groups {xcd, xcd+8, xcd+16}, 25 q-tiles each
  int bid = blockIdx.x;
  int xcd = bid & 7, slot = bid >> 3;
  int g = xcd + 8 * (slot / 25);
  int mt = slot % 25;
  const int m0 = mt * 64;
  const int h = g >> 1, t = g & 1;

  int s0 = sel[2 * t];
  const int b0 = s0 > 0 ? s0 : 0;
  const int b1 = sel[2 * t + 1];
  const int nk = (b1 >= 0) ? 2 * HWc : HWc;
  const int nch = (nk + 63) >> 6;

  // Q B-frags
  u16x8 qf[4][4];
#pragma unroll
  for (int qt = 0; qt < 4; ++qt) {
    int qrow = m0 + qt * 16 + l15;
    if (qrow > HWc - 1) qrow = HWc - 1;
    const u16* qp = Q + (size_t)(t * HWc + qrow) * DIMc + h * 128;
#pragma unroll
    for (int ks = 0; ks < 4; ++ks) qf[qt][ks] = *(const u16x8*)(qp + ks * 32 + quad * 8);
  }

  f32x4 oacc[2][4];
#pragma unroll
  for (int nt = 0; nt < 2; ++nt)
#pragma unroll
    for (int qt = 0; qt < 4; ++qt)
#pragma unroll
      for (int r = 0; r < 4; ++r) oacc[nt][qt][r] = 0.f;
  float lp[4] = {0.f, 0.f, 0.f, 0.f};

  const int kl_r = lane >> 4, kl_c = lane & 15;
  const int vl_r = lane >> 3, vl_c = lane & 7;

  auto stage = [&](int kc, int buf) {
    u16* Ks = smem + buf * 8192;
    u16* Vt = smem + 16384 + buf * 8192;
#pragma unroll
    for (int n = 0; n < 4; ++n) {
      int keyl = wid * 16 + n * 4 + kl_r;
      int gc = kl_c ^ (keyl & 15);
      int kg = kc + keyl;
      if (kg >= nk) kg = 0;
      int big = kg >= HWc;
      int tok = (big ? b1 : b0) * HWc + kg - (big ? HWc : 0);
      glds16(Kb + ((size_t)tok * DIMc + h * 128 + gc * 8), Ks + (wid * 16 + n * 4) * 128);
    }
#pragma unroll
    for (int n = 0; n < 4; ++n) {
      int dl = wid * 32 + n * 8 + vl_r;
      int gc = vl_c ^ (dl & 7);
      int tg = kc + gc * 8;
      if (tg >= nk) tg = 0;
      int big = tg >= HWc;
      int tok = (big ? b1 : b0) * HWc + tg - (big ? HWc : 0);
      glds16(VT + ((size_t)(h * 128 + dl) * KTt + tok), Vt + (wid * 32 + n * 8) * 64);
    }
  };

  stage(0, 0);

  for (int c = 0; c < nch; ++c) {
    const int buf = c & 1;
    u16* Ks = smem + buf * 8192;
    u16* Vt = smem + 16384 + buf * 8192;
    // wait own prefetch of chunk c, then sync all waves (their prefetches also done)
    asm volatile("s_waitcnt vmcnt(0)\n\ts_barrier" ::: "memory");
    if (c + 1 < nch) stage((c + 1) * 64, buf ^ 1);

    // S^T = K Q^T for this wave's 16 keys
    f32x4 s[4];
#pragma unroll
    for (int qt = 0; qt < 4; ++qt)
#pragma unroll
      for (int r = 0; r < 4; ++r) s[qt][r] = 0.f;
#pragma unroll
    for (int ks = 0; ks < 4; ++ks) {
      int key = wid * 16 + l15;
      u16x8 ka = *(const u16x8*)&Ks[key * 128 + (((ks * 4 + quad) ^ l15) * 8)];
#pragma unroll
      for (int qt = 0; qt < 4; ++qt) s[qt] = mfma16(ka, qf[qt][ks], s[qt]);
    }
    // one-pass softmax numerator p = 2^s, mask invalid keys
    int kb_ = c * 64 + wid * 16 + quad * 4;
#pragma unroll
    for (int qt = 0; qt < 4; ++qt) {
      u16x4 pw;
#pragma unroll
      for (int r = 0; r < 4; ++r) {
        float p = (kb_ + r < nk) ? exp2f(s[qt][r]) : 0.f;
        lp[qt] += p;
        pw[r] = f2bf(p);
      }
      *(u16x4*)&Ps[(qt * 16 + l15) * 68 + wid * 16 + quad * 4] = pw;
    }
    // Ps exchange: LDS-only barrier — do NOT drain vmcnt (prefetch in flight)
    asm volatile("s_waitcnt lgkmcnt(0)\n\ts_barrier" ::: "memory");

    // O^T += V^T P^T for this wave's 32 d rows
#pragma unroll
    for (int k2 = 0; k2 < 2; ++k2) {
      u16x8 pf[4];
#pragma unroll
      for (int qt = 0; qt < 4; ++qt)
        pf[qt] = *(const u16x8*)&Ps[(qt * 16 + l15) * 68 + k2 * 32 + quad * 8];
#pragma unroll
      for (int nt = 0; nt < 2; ++nt) {
        int d = wid * 32 + nt * 16 + l15;
        u16x8 va = *(const u16x8*)&Vt[d * 64 + (((k2 * 4 + quad) ^ (d & 7)) * 8)];
#pragma unroll
        for (int qt = 0; qt < 4; ++qt) oacc[nt][qt] = mfma16(va, pf[qt], oacc[nt][qt]);
      }
    }
    // no trailing barrier: next-iteration top barrier protects buffer reuse
  }

  // l merge across quads then waves
#pragma unroll
  for (int qt = 0; qt < 4; ++qt) {
    float v = lp[qt];
    v += __shfl_xor(v, 16);
    v += __shfl_xor(v, 32);
    if (lane < 16) Ls[wid][qt * 16 + lane] = v;
  }
  __syncthreads();  // all waves past PV reads; no vmem outstanding on last chunk

  // epilogue: per-wave O^T staging (alias smem), then coalesced bf16 store
  float* Ot = (float*)smem + wid * 2304;  // [64 q][36]
#pragma unroll
  for (int nt = 0; nt < 2; ++nt)
#pragma unroll
    for (int qt = 0; qt < 4; ++qt)
      *(f32x4*)&Ot[(qt * 16 + l15) * 36 + nt * 16 + quad * 4] = oacc[nt][qt];
  asm volatile("s_waitcnt lgkmcnt(0)" ::: "memory");
  int qrow = m0 + lane;
  if (qrow < HWc) {
    float l = Ls[0][lane] + Ls[1][lane] + Ls[2][lane] + Ls[3][lane];
    float inv = 1.f / l;
    u16* op = O + (size_t)(t * HWc + qrow) * DIMc + h * 128 + wid * 32;
#pragma unroll
    for (int j = 0; j < 4; ++j) {
      f32x4 a = *(const f32x4*)&Ot[lane * 36 + j * 8];
      f32x4 b = *(const f32x4*)&Ot[lane * 36 + j * 8 + 4];
      u16x8 o8;
#pragma unroll
      for (int e = 0; e < 4; ++e) { o8[e] = f2bf(a[e] * inv); o8[e + 4] = f2bf(b[e] * inv); }
      *(u16x8*)(op + j * 8) = o8;
    }
  }
}

extern "C" void kernel_launch(void* const* d_in, const int* in_sizes, int n_in,
                              void* d_out, int out_size, void* d_ws, size_t ws_size,
                              hipStream_t stream) {
  const float* hs  = (const float*)d_in[0];
  const float* his = (const float*)d_in[1];
  const float* fc  = (const float*)d_in[2];
  const float* fs  = (const float*)d_in[3];
  const float* fch = (const float*)d_in[4];
  const float* fsh = (const float*)d_in[5];
  const int*   sel = (const int*)d_in[6];
  const float* Wq  = (const float*)d_in[7];
  const float* bq  = (const float*)d_in[8];
  const float* Wk  = (const float*)d_in[9];
  const float* bk  = (const float*)d_in[10];
  const float* Wv  = (const float*)d_in[11];
  const float* bv  = (const float*)d_in[12];
  const float* Wo  = (const float*)d_in[13];
  const float* bo  = (const float*)d_in[14];
  const float* gq  = (const float*)d_in[15];
  const float* gk  = (const float*)d_in[16];

  const int QT = 3120, KT = 12480, DIMc = 1536;
  u16* p = (u16*)d_ws;
  u16* hsb = p; p += (size_t)QT * DIMc;
  u16* hib = p; p += (size_t)KT * DIMc;
  u16* wqb = p; p += (size_t)DIMc * DIMc;
  u16* wkb = p; p += (size_t)DIMc * DIMc;
  u16* wvb = p; p += (size_t)DIMc * DIMc;
  u16* wob = p; p += (size_t)DIMc * DIMc;
  u16* qb  = p; p += (size_t)QT * DIMc;
  u16* kb2 = p; p += (size_t)KT * DIMc;
  u16* ab  = p; p += (size_t)QT * DIMc;   // ab before vt so GEMM A-tail overreads stay in ws
  u16* vt  = p; p += (size_t)DIMc * KT;   // V^T [1536][12480]

  cvt_bf16<<<dim3((QT * DIMc / 4 + 255) / 256), 256, 0, stream>>>(hs, hsb, QT * DIMc / 4);
  cvt_bf16<<<dim3((KT * DIMc / 4 + 255) / 256), 256, 0, stream>>>(his, hib, KT * DIMc / 4);
  cvt_w4<<<dim3(2304, 4), 256, 0, stream>>>(Wq, Wk, Wv, Wo, wqb, wkb, wvb, wob);

  gemm_v2<0><<<dim3(12, 25), 256, 0, stream>>>(hsb, wqb, bq, qb, QT, 0);
  gemm_v2<0><<<dim3(12, 98), 256, 0, stream>>>(hib, wkb, bk, kb2, KT, 0);
  gemm_v2<2><<<dim3(12, 98), 256, 0, stream>>>(hib, wvb, bv, vt, KT, KT);  // writes V^T

  const float qscale = (float)(0.08838834764831845 * 1.4426950408889634);
  norm_rope2<<<dim3(QT), 192, 0, stream>>>(qb, gq, fc, fs, qscale);
  norm_rope2<<<dim3(KT), 192, 0, stream>>>(kb2, gk, fch, fsh, 1.0f);

  attn3<<<dim3(600), 256, 0, stream>>>(qb, kb2, vt, sel, ab);

  gemm_v2<1><<<dim3(12, 25), 256, 0, stream>>>(ab, wob, bo, d_out, QT, 0);
}

// Round 4
// 663.961 us; speedup vs baseline: 1.1120x; 1.1120x over previous
//
#include <hip/hip_runtime.h>

typedef unsigned short u16;
typedef __attribute__((ext_vector_type(4))) unsigned short u16x4;
typedef __attribute__((ext_vector_type(8))) unsigned short u16x8;
typedef __attribute__((ext_vector_type(4))) short s16x4;
typedef __attribute__((ext_vector_type(4))) float f32x4;
typedef __attribute__((ext_vector_type(8))) __bf16 bf16x8;

__device__ __forceinline__ u16 f2bf(float f) {
  union { float f; unsigned int u; } v; v.f = f;
  unsigned int u = v.u;
  unsigned int r = (u + 0x7fffu + ((u >> 16) & 1u)) >> 16;
  return (u16)r;
}
__device__ __forceinline__ float bf2f(u16 h) {
  union { unsigned int u; float f; } v; v.u = ((unsigned int)h) << 16;
  return v.f;
}
__device__ __forceinline__ f32x4 mfma16(u16x8 a, u16x8 b, f32x4 c) {
  return __builtin_amdgcn_mfma_f32_16x16x32_bf16(
      __builtin_bit_cast(bf16x8, a), __builtin_bit_cast(bf16x8, b), c, 0, 0, 0);
}
// K=16 variant: A/B are 4 bf16 (2 VGPRs)
__device__ __forceinline__ f32x4 mfma16k16(u16x4 a, u16x4 b, f32x4 c) {
  return __builtin_amdgcn_mfma_f32_16x16x16bf16_1k(
      __builtin_bit_cast(s16x4, a), __builtin_bit_cast(s16x4, b), c, 0, 0, 0);
}
// async global->LDS, 16B per lane; LDS dest = wave-uniform base + lane*16
__device__ __forceinline__ void glds16(const void* g, void* l) {
  __builtin_amdgcn_global_load_lds((const __attribute__((address_space(1))) void*)g,
                                   (__attribute__((address_space(3))) void*)l, 16, 0, 0);
}

// ---------------- fp32 -> bf16 conversion ----------------
__global__ __launch_bounds__(256) void cvt_bf16(const float* __restrict__ x,
                                                u16* __restrict__ y, int n4) {
  int i = blockIdx.x * 256 + threadIdx.x;
  if (i >= n4) return;
  float4 v = ((const float4*)x)[i];
  u16x4 o;
  o.x = f2bf(v.x); o.y = f2bf(v.y); o.z = f2bf(v.z); o.w = f2bf(v.w);
  ((u16x4*)y)[i] = o;
}
__global__ __launch_bounds__(256) void cvt_w4(const float* __restrict__ a, const float* __restrict__ b,
                                              const float* __restrict__ c, const float* __restrict__ d,
                                              u16* __restrict__ oa, u16* __restrict__ ob,
                                              u16* __restrict__ oc, u16* __restrict__ od) {
  int w = blockIdx.y;
  const float* s = w == 0 ? a : w == 1 ? b : w == 2 ? c : d;
  u16* o = w == 0 ? oa : w == 1 ? ob : w == 2 ? oc : od;
  int i = blockIdx.x * 256 + threadIdx.x;
  float4 v = ((const float4*)s)[i];
  u16x4 r;
  r.x = f2bf(v.x); r.y = f2bf(v.y); r.z = f2bf(v.z); r.w = f2bf(v.w);
  ((u16x4*)o)[i] = r;
}

// ---------------- GEMM: C[M,1536] = A[M,1536] @ W[1536,1536]^T + bias ----------------
template <int OUT>  // 0 = bf16, 1 = f32, 2 = bf16 transposed (C^T[N][ldt])
__global__ __launch_bounds__(256, 2) void gemm_v2(
    const u16* __restrict__ A, const u16* __restrict__ W,
    const float* __restrict__ bias, void* __restrict__ Cp, int M, int ldt) {
  const int K = 1536, N = 1536;
  __shared__ __align__(16) u16 gsm[17408];
  u16* As = gsm;
  u16* Bs = gsm + 8192;
  const int tid = threadIdx.x;
  const int lane = tid & 63, wid = tid >> 6;
  const int quad = lane >> 4, l15 = lane & 15;
  const int m0 = blockIdx.y * 128, n0 = blockIdx.x * 128;
  const int wm = (wid >> 1) * 64, wn = (wid & 1) * 64;
  f32x4 acc[4][4];
#pragma unroll
  for (int i = 0; i < 4; ++i)
#pragma unroll
    for (int j = 0; j < 4; ++j)
#pragma unroll
      for (int r = 0; r < 4; ++r) acc[i][j][r] = 0.f;

  const int r8 = lane >> 3, c8 = lane & 7;
  const int gch = c8 ^ r8;

  for (int k0 = 0; k0 < K; k0 += 64) {
#pragma unroll
    for (int inst = 0; inst < 4; ++inst) {
      int row = wid * 32 + inst * 8 + r8;
      glds16(A + ((size_t)(m0 + row) * K + k0 + gch * 8), As + (wid * 32 + inst * 8) * 64);
      glds16(W + ((size_t)(n0 + row) * K + k0 + gch * 8), Bs + (wid * 32 + inst * 8) * 64);
    }
    asm volatile("s_waitcnt vmcnt(0)" ::: "memory");
    __syncthreads();
#pragma unroll
    for (int ks = 0; ks < 2; ++ks) {
      u16x8 af[4], bfr[4];
#pragma unroll
      for (int i = 0; i < 4; ++i) {
        int row = wm + i * 16 + l15;
        af[i] = *(const u16x8*)&As[row * 64 + (((ks * 4 + quad) ^ (l15 & 7)) * 8)];
      }
#pragma unroll
      for (int j = 0; j < 4; ++j) {
        int row = wn + j * 16 + l15;
        bfr[j] = *(const u16x8*)&Bs[row * 64 + (((ks * 4 + quad) ^ (l15 & 7)) * 8)];
      }
#pragma unroll
      for (int i = 0; i < 4; ++i)
#pragma unroll
        for (int j = 0; j < 4; ++j) acc[i][j] = mfma16(af[i], bfr[j], acc[i][j]);
    }
    __syncthreads();
  }

  if (OUT != 2) {
#pragma unroll
    for (int i = 0; i < 4; ++i) {
      int row = m0 + wm + i * 16 + quad * 4;
#pragma unroll
      for (int j = 0; j < 4; ++j) {
        int col = n0 + wn + j * 16 + l15;
        float bc = bias[col];
#pragma unroll
        for (int r = 0; r < 4; ++r) {
          if (row + r < M) {
            float v = acc[i][j][r] + bc;
            if (OUT == 1)
              ((float*)Cp)[(size_t)(row + r) * N + col] = v;
            else
              ((u16*)Cp)[(size_t)(row + r) * N + col] = f2bf(v);
          }
        }
      }
    }
  } else {
    u16* Ct = gsm;  // [128 n][136]
#pragma unroll
    for (int i = 0; i < 4; ++i)
#pragma unroll
      for (int j = 0; j < 4; ++j) {
        int nloc = wn + j * 16 + l15;
        float bc = bias[n0 + nloc];
#pragma unroll
        for (int r = 0; r < 4; ++r) {
          int mloc = wm + i * 16 + quad * 4 + r;
          Ct[nloc * 136 + mloc] = f2bf(acc[i][j][r] + bc);
        }
      }
    __syncthreads();
    int n = tid >> 1, half = tid & 1;
#pragma unroll
    for (int e = 0; e < 8; ++e) {
      int mloc = half * 64 + e * 8;
      if (m0 + mloc < M) {
        u16x8 v = *(const u16x8*)&Ct[n * 136 + mloc];
        *(u16x8*)((u16*)Cp + (size_t)(n0 + n) * ldt + m0 + mloc) = v;
      }
    }
  }
}

// ---------------- fused RMSNorm + interleaved RoPE, in-place bf16 ----------------
__global__ __launch_bounds__(192) void norm_rope2(u16* __restrict__ X,
                                                  const float* __restrict__ g,
                                                  const float* __restrict__ fc,
                                                  const float* __restrict__ fs,
                                                  float oscale) {
  const int DIMc = 1536;
  int row = blockIdx.x;
  int tid = threadIdx.x;
  u16* xr = X + (size_t)row * DIMc + tid * 8;
  u16x8 v = *(const u16x8*)xr;
  float x[8];
  float ss = 0.f;
#pragma unroll
  for (int e = 0; e < 8; ++e) { x[e] = bf2f(v[e]); ss += x[e] * x[e]; }
#pragma unroll
  for (int m = 1; m < 64; m <<= 1) ss += __shfl_xor(ss, m);
  __shared__ float w3[3];
  if ((tid & 63) == 0) w3[tid >> 6] = ss;
  __syncthreads();
  float rs = rsqrtf((w3[0] + w3[1] + w3[2]) * (1.f / 1536.f) + 1e-5f);
  int dhb = (tid * 8) & 127;
  const float* fcr = fc + (size_t)row * 128 + dhb;
  const float* fsr = fs + (size_t)row * 128 + dhb;
  float4 c0 = *(const float4*)fcr, c1 = *(const float4*)(fcr + 4);
  float4 s0 = *(const float4*)fsr, s1 = *(const float4*)(fsr + 4);
  const float* gp = g + tid * 8;
  float4 g0 = *(const float4*)gp, g1 = *(const float4*)(gp + 4);
  float cosv[4] = {c0.x, c0.z, c1.x, c1.z};
  float sinv[4] = {s0.y, s0.w, s1.y, s1.w};
  float gv[8] = {g0.x, g0.y, g0.z, g0.w, g1.x, g1.y, g1.z, g1.w};
  u16x8 o;
#pragma unroll
  for (int p = 0; p < 4; ++p) {
    float a = x[2 * p] * rs * gv[2 * p];
    float b = x[2 * p + 1] * rs * gv[2 * p + 1];
    o[2 * p] = f2bf((a * cosv[p] - b * sinv[p]) * oscale);
    o[2 * p + 1] = f2bf((a * sinv[p] + b * cosv[p]) * oscale);
  }
  *(u16x8*)xr = o;
}

// ---------------- block-sparse attention v4: key-split, zero P round-trip ----------------
// 128-thr blocks (2 waves), 32-key double-buffered chunks. Wave w owns 16 keys/chunk,
// computes S^T C-frags and feeds them directly as B-operands of K=16 PV mfma
// (C layout row=quad*4+r,col=l15 == B layout k=quad*4+j,n=l15). Partial O^T per wave,
// merged once at the end. One barrier per chunk.
__global__ __launch_bounds__(128, 2) void attn4(
    const u16* __restrict__ Q, const u16* __restrict__ Kb,
    const u16* __restrict__ VT, const int* __restrict__ sel,
    u16* __restrict__ O) {
  const int HWc = 1560, DIMc = 1536, KTt = 12480;
  __shared__ __align__(16) u16 smem[16384];  // Ks0|Ks1|Vt0|Vt1 (8 KB each); merge reuses all 32 KB
  __shared__ float Ls[2][64];
  const int tid = threadIdx.x;
  const int lane = tid & 63, wid = tid >> 6;
  const int quad = lane >> 4, l15 = lane & 15;

  // XCD swizzle: all 25 q-tiles of one (h,t) on one XCD (keeps FETCH ~20 MB)
  int bid = blockIdx.x;
  int xcd = bid & 7, slot = bid >> 3;
  int g = xcd + 8 * (slot / 25);
  int mt = slot % 25;
  const int m0 = mt * 64;
  const int h = g >> 1, t = g & 1;

  int s0 = sel[2 * t];
  const int b0 = s0 > 0 ? s0 : 0;
  const int b1 = sel[2 * t + 1];
  const int nk = (b1 >= 0) ? 2 * HWc : HWc;
  const int nch = (nk + 31) >> 5;

  // Q B-frags (all 64 q per wave)
  u16x8 qf[4][4];
#pragma unroll
  for (int qt = 0; qt < 4; ++qt) {
    int qrow = m0 + qt * 16 + l15;
    if (qrow > HWc - 1) qrow = HWc - 1;
    const u16* qp = Q + (size_t)(t * HWc + qrow) * DIMc + h * 128;
#pragma unroll
    for (int ks = 0; ks < 4; ++ks) qf[qt][ks] = *(const u16x8*)(qp + ks * 32 + quad * 8);
  }

  f32x4 oacc[8][4];  // partial O^T: [d-tile][q-tile]
#pragma unroll
  for (int m = 0; m < 8; ++m)
#pragma unroll
    for (int qt = 0; qt < 4; ++qt)
#pragma unroll
      for (int r = 0; r < 4; ++r) oacc[m][qt][r] = 0.f;
  float lp[4] = {0.f, 0.f, 0.f, 0.f};

  auto stage = [&](int kc, int buf) {
    u16* Ks = smem + buf * 4096;
    u16* Vt = smem + 8192 + buf * 4096;
    // K rows: wave w stages keys w*16..+16 (4 glds, 4 rows x 16 chunks each)
#pragma unroll
    for (int n = 0; n < 4; ++n) {
      int kl = wid * 16 + n * 4 + (lane >> 4);
      int gc = (lane & 15) ^ (kl & 15);
      int kg = kc + kl;
      if (kg >= nk) kg = 0;
      int big = kg >= HWc;
      int tok = (big ? b1 : b0) * HWc + kg - (big ? HWc : 0);
      glds16(Kb + ((size_t)tok * DIMc + h * 128 + gc * 8), Ks + (wid * 16 + n * 4) * 128);
    }
    // V^T rows: wave w stages d rows w*64..+64 (4 glds, 16 rows x 4 chunks each)
#pragma unroll
    for (int n = 0; n < 4; ++n) {
      int dl = wid * 64 + n * 16 + (lane >> 2);
      int gc = (lane & 3) ^ (dl & 3);
      int tg = kc + gc * 8;
      if (tg >= nk) tg = 0;
      int big = tg >= HWc;
      int tok = (big ? b1 : b0) * HWc + tg - (big ? HWc : 0);
      glds16(VT + ((size_t)(h * 128 + dl) * KTt + tok), Vt + (wid * 64 + n * 16) * 32);
    }
  };

  stage(0, 0);

  for (int c = 0; c < nch; ++c) {
    const int buf = c & 1;
    u16* Ks = smem + buf * 4096;
    u16* Vt = smem + 8192 + buf * 4096;
    asm volatile("s_waitcnt vmcnt(0)\n\ts_barrier" ::: "memory");
    if (c + 1 < nch) stage((c + 1) * 32, buf ^ 1);

    // S^T = K Q^T for this wave's 16 keys
    f32x4 s[4];
#pragma unroll
    for (int qt = 0; qt < 4; ++qt)
#pragma unroll
      for (int r = 0; r < 4; ++r) s[qt][r] = 0.f;
    const int kl = wid * 16 + l15;
#pragma unroll
    for (int ks = 0; ks < 4; ++ks) {
      u16x8 ka = *(const u16x8*)&Ks[kl * 128 + (((ks * 4 + quad) ^ l15) * 8)];
#pragma unroll
      for (int qt = 0; qt < 4; ++qt) s[qt] = mfma16(ka, qf[qt][ks], s[qt]);
    }
    // p = 2^s (one-pass softmax), convert to bf16 B-frags in-lane
    const int kb_ = c * 32 + wid * 16 + quad * 4;
    u16x4 pb[4];
#pragma unroll
    for (int qt = 0; qt < 4; ++qt) {
#pragma unroll
      for (int r = 0; r < 4; ++r) {
        float p = (kb_ + r < nk) ? exp2f(s[qt][r]) : 0.f;
        lp[qt] += p;
        pb[qt][r] = f2bf(p);
      }
    }
    // partial O^T += V^T(own keys) · P^T(own keys): K=16 mfma, B straight from C-frags
#pragma unroll
    for (int m = 0; m < 8; ++m) {
      int d = m * 16 + l15;
      u16x4 va = *(const u16x4*)&Vt[d * 32 + (((wid * 2 + (quad >> 1)) ^ (d & 3)) * 8) + (quad & 1) * 4];
#pragma unroll
      for (int qt = 0; qt < 4; ++qt) oacc[m][qt] = mfma16k16(va, pb[qt], oacc[m][qt]);
    }
  }

  // softmax denominator: reduce over quads, publish per wave
#pragma unroll
  for (int qt = 0; qt < 4; ++qt) {
    float v = lp[qt];
    v += __shfl_xor(v, 16);
    v += __shfl_xor(v, 32);
    if (lane < 16) Ls[wid][qt * 16 + lane] = v;
  }
  __syncthreads();  // also: all waves done with staging buffers

  // O merge: wave 1 parks its partial in LDS (32 KB), wave 0 adds + stores
  float* mb = (float*)smem;
  if (wid == 1) {
#pragma unroll
    for (int m = 0; m < 8; ++m)
#pragma unroll
      for (int qt = 0; qt < 4; ++qt)
        *(f32x4*)&mb[((m * 4 + qt) * 64 + lane) * 4] = oacc[m][qt];
  }
  __syncthreads();
  if (wid == 0) {
    float linv[4];
#pragma unroll
    for (int qt = 0; qt < 4; ++qt)
      linv[qt] = 1.f / (Ls[0][qt * 16 + l15] + Ls[1][qt * 16 + l15]);
#pragma unroll
    for (int m = 0; m < 8; ++m) {
#pragma unroll
      for (int qt = 0; qt < 4; ++qt) {
        f32x4 ov = *(const f32x4*)&mb[((m * 4 + qt) * 64 + lane) * 4];
        int q = m0 + qt * 16 + l15;
        if (q < HWc) {
          u16x4 o4;
#pragma unroll
          for (int r = 0; r < 4; ++r) o4[r] = f2bf((oacc[m][qt][r] + ov[r]) * linv[qt]);
          *(u16x4*)(O + (size_t)(t * HWc + q) * DIMc + h * 128 + m * 16 + quad * 4) = o4;
        }
      }
    }
  }
}

extern "C" void kernel_launch(void* const* d_in, const int* in_sizes, int n_in,
                              void* d_out, int out_size, void* d_ws, size_t ws_size,
                              hipStream_t stream) {
  const float* hs  = (const float*)d_in[0];
  const float* his = (const float*)d_in[1];
  const float* fc  = (const float*)d_in[2];
  const float* fs  = (const float*)d_in[3];
  const float* fch = (const float*)d_in[4];
  const float* fsh = (const float*)d_in[5];
  const int*   sel = (const int*)d_in[6];
  const float* Wq  = (const float*)d_in[7];
  const float* bq  = (const float*)d_in[8];
  const float* Wk  = (const float*)d_in[9];
  const float* bk  = (const float*)d_in[10];
  const float* Wv  = (const float*)d_in[11];
  const float* bv  = (const float*)d_in[12];
  const float* Wo  = (const float*)d_in[13];
  const float* bo  = (const float*)d_in[14];
  const float* gq  = (const float*)d_in[15];
  const float* gk  = (const float*)d_in[16];

  const int QT = 3120, KT = 12480, DIMc = 1536;
  u16* p = (u16*)d_ws;
  u16* hsb = p; p += (size_t)QT * DIMc;
  u16* hib = p; p += (size_t)KT * DIMc;
  u16* wqb = p; p += (size_t)DIMc * DIMc;
  u16* wkb = p; p += (size_t)DIMc * DIMc;
  u16* wvb = p; p += (size_t)DIMc * DIMc;
  u16* wob = p; p += (size_t)DIMc * DIMc;
  u16* qb  = p; p += (size_t)QT * DIMc;
  u16* kb2 = p; p += (size_t)KT * DIMc;
  u16* ab  = p; p += (size_t)QT * DIMc;
  u16* vt  = p; p += (size_t)DIMc * KT;   // V^T [1536][12480]

  cvt_bf16<<<dim3((QT * DIMc / 4 + 255) / 256), 256, 0, stream>>>(hs, hsb, QT * DIMc / 4);
  cvt_bf16<<<dim3((KT * DIMc / 4 + 255) / 256), 256, 0, stream>>>(his, hib, KT * DIMc / 4);
  cvt_w4<<<dim3(2304, 4), 256, 0, stream>>>(Wq, Wk, Wv, Wo, wqb, wkb, wvb, wob);

  gemm_v2<0><<<dim3(12, 25), 256, 0, stream>>>(hsb, wqb, bq, qb, QT, 0);
  gemm_v2<0><<<dim3(12, 98), 256, 0, stream>>>(hib, wkb, bk, kb2, KT, 0);
  gemm_v2<2><<<dim3(12, 98), 256, 0, stream>>>(hib, wvb, bv, vt, KT, KT);  // writes V^T

  const float qscale = (float)(0.08838834764831845 * 1.4426950408889634);
  norm_rope2<<<dim3(QT), 192, 0, stream>>>(qb, gq, fc, fs, qscale);
  norm_rope2<<<dim3(KT), 192, 0, stream>>>(kb2, gk, fch, fsh, 1.0f);

  attn4<<<dim3(600), 128, 0, stream>>>(qb, kb2, vt, sel, ab);

  gemm_v2<1><<<dim3(12, 25), 256, 0, stream>>>(ab, wob, bo, d_out, QT, 0);
}